// Round 1
// baseline (25.427 us; speedup 1.0000x reference)
//
#include <hip/hip_runtime.h>
#include <hip/hip_bf16.h>

#define FDIM 1024
#define KNZ 32
#define NROWS 2048
#define RB 8          // rows per block
#define TPB 1024      // threads per block == FDIM (o = tid)
#define EPSV 1e-6f

static_assert(TPB == FDIM, "o = tid mapping requires TPB == FDIM");
static_assert(NROWS % RB == 0, "rows divide");

// granule swizzle: spreads structured f-sequences across the 8 bank-quads
__device__ __forceinline__ unsigned int swz(unsigned int i) {
  return i ^ ((i >> 3) & 7u);
}

__device__ __forceinline__ unsigned int f2bf(float f) {
  unsigned int u = __float_as_uint(f);
  u += 0x7fffu + ((u >> 16) & 1u);   // RNE
  return u >> 16;
}

__device__ __forceinline__ unsigned int pack2bf(float a, float b) {
  return f2bf(a) | (f2bf(b) << 16);
}

// Build transposed (lds_granule_offset, weight) pairs: pr[k*FDIM + o]
// so the main kernel's k-loop weight loads are coalesced across lanes (lane = o).
__global__ void geo_prep(const int* __restrict__ idx,
                         const float* __restrict__ w1,
                         const float* __restrict__ w2,
                         int2* __restrict__ pr1, int2* __restrict__ pr2) {
  __shared__ int   li[16 * 33];
  __shared__ float l1[16 * 33];
  __shared__ float l2[16 * 33];
  const int t = threadIdx.x;       // 256 threads
  const int o0 = blockIdx.x * 16;  // 16 outputs per block
  #pragma unroll
  for (int e = 0; e < 2; ++e) {
    int j = t + e * 256;           // 0..511, coalesced global read
    int ol = j >> 5, k = j & 31;
    int g = o0 * KNZ + j;
    li[ol * 33 + k] = idx[g];
    l1[ol * 33 + k] = w1[g];
    l2[ol * 33 + k] = w2[g];
  }
  __syncthreads();
  #pragma unroll
  for (int e = 0; e < 2; ++e) {
    int j = t + e * 256;
    int ol = j & 15, k = j >> 4;   // consecutive t -> consecutive o: coalesced write
    int i = li[ol * 33 + k];
    int off = (int)swz((unsigned)i);
    pr1[k * FDIM + o0 + ol] = make_int2(off, __float_as_int(l1[ol * 33 + k]));
    pr2[k * FDIM + o0 + ol] = make_int2(off, __float_as_int(l2[ol * 33 + k]));
  }
}

template <bool TR>
__global__ __launch_bounds__(TPB)
void geo_main(const float* __restrict__ x, const float* __restrict__ norm_w,
              const float* __restrict__ b1, const float* __restrict__ amp,
              const float* __restrict__ freq, const float* __restrict__ decay,
              const float* __restrict__ b2, const float* __restrict__ alpha,
              const int2* __restrict__ pr1, const int2* __restrict__ pr2,
              const int* __restrict__ idx, const float* __restrict__ w1,
              const float* __restrict__ w2, float* __restrict__ out) {
  // granule f holds rows 0..7 of feature f as 8 bf16 (dword d = rows 2d|2d+1)
  __shared__ uint4 h_lds[FDIM];            // 16 KB
  __shared__ uint4 s_lds[FDIM];            // 16 KB
  __shared__ float red[TPB / 64][RB];
  __shared__ float rs_sh[RB];

  const int tid = threadIdx.x;
  const int wid = tid >> 6;
  const int r0 = blockIdx.x * RB;

  // ---------- Phase A: load x, RMSNorm, write h (bf16) transposed into LDS ----------
  float v[RB];
  #pragma unroll
  for (int r = 0; r < RB; ++r)
    v[r] = x[(r0 + r) * FDIM + tid];       // coalesced per row

  #pragma unroll
  for (int r = 0; r < RB; ++r) {
    float p = v[r] * v[r];
    #pragma unroll
    for (int s = 32; s > 0; s >>= 1) p += __shfl_xor(p, s, 64);
    if ((tid & 63) == 0) red[wid][r] = p;
  }
  __syncthreads();
  if (tid < RB) {
    float s = 0.f;
    #pragma unroll
    for (int w = 0; w < TPB / 64; ++w) s += red[w][tid];
    rs_sh[tid] = rsqrtf(s * (1.0f / FDIM) + EPSV);
  }
  __syncthreads();
  {
    const float g = norm_w[tid];
    float rsv[RB];
    #pragma unroll
    for (int r = 0; r < RB; ++r) rsv[r] = rs_sh[r];
    uint4 h;
    h.x = pack2bf(v[0] * rsv[0] * g, v[1] * rsv[1] * g);
    h.y = pack2bf(v[2] * rsv[2] * g, v[3] * rsv[3] * g);
    h.z = pack2bf(v[4] * rsv[4] * g, v[5] * rsv[5] * g);
    h.w = pack2bf(v[6] * rsv[6] * g, v[7] * rsv[7] * g);
    h_lds[swz((unsigned)tid)] = h;         // conflict-free under swz
  }
  __syncthreads();

  const int o = tid;

  // ---------- Stage 1: z = gather(h)·w1 + b1 ; s = amp*sin(freq z)*exp(-decay z^2) ----------
  float acc[RB] = {0.f, 0.f, 0.f, 0.f, 0.f, 0.f, 0.f, 0.f};
  #pragma unroll 8
  for (int k = 0; k < KNZ; ++k) {
    int off; float w;
    if (TR) {
      int2 pw = pr1[k * FDIM + o];         // coalesced dwordx2
      off = pw.x; w = __int_as_float(pw.y);
    } else {
      off = (int)swz((unsigned)idx[o * KNZ + k]);
      w = w1[o * KNZ + k];
    }
    uint4 hv = h_lds[off];                 // ds_read_b128: 8 rows for this (o,k)
    const unsigned int* hd = reinterpret_cast<const unsigned int*>(&hv);
    #pragma unroll
    for (int d = 0; d < 4; ++d) {
      float lo = __uint_as_float(hd[d] << 16);
      float hi = __uint_as_float(hd[d] & 0xffff0000u);
      acc[2 * d]     = fmaf(lo, w, acc[2 * d]);
      acc[2 * d + 1] = fmaf(hi, w, acc[2 * d + 1]);
    }
  }
  {
    const float bb = b1[o], am = amp[o], fq = freq[o], dc = decay[o];
    float s[RB];
    #pragma unroll
    for (int r = 0; r < RB; ++r) {
      float z = acc[r] + bb;
      s[r] = am * __sinf(fq * z) * __expf(-dc * z * z);
    }
    uint4 sv;
    sv.x = pack2bf(s[0], s[1]);
    sv.y = pack2bf(s[2], s[3]);
    sv.z = pack2bf(s[4], s[5]);
    sv.w = pack2bf(s[6], s[7]);
    s_lds[swz((unsigned)o)] = sv;          // conflict-free under swz
  }
  __syncthreads();

  // ---------- Stage 2: h2 = gather(s)·w2 + b2 ; out = x + alpha*h2 ----------
  #pragma unroll
  for (int r = 0; r < RB; ++r) acc[r] = 0.f;
  #pragma unroll 8
  for (int k = 0; k < KNZ; ++k) {
    int off; float w;
    if (TR) {
      int2 pw = pr2[k * FDIM + o];
      off = pw.x; w = __int_as_float(pw.y);
    } else {
      off = (int)swz((unsigned)idx[o * KNZ + k]);
      w = w2[o * KNZ + k];
    }
    uint4 sv = s_lds[off];
    const unsigned int* sd = reinterpret_cast<const unsigned int*>(&sv);
    #pragma unroll
    for (int d = 0; d < 4; ++d) {
      float lo = __uint_as_float(sd[d] << 16);
      float hi = __uint_as_float(sd[d] & 0xffff0000u);
      acc[2 * d]     = fmaf(lo, w, acc[2 * d]);
      acc[2 * d + 1] = fmaf(hi, w, acc[2 * d + 1]);
    }
  }
  {
    const float bb = b2[o];
    const float al = alpha[0];
    #pragma unroll
    for (int r = 0; r < RB; ++r)
      out[(r0 + r) * FDIM + o] = v[r] + al * (acc[r] + bb);  // v[r] = x, still in regs
  }
}

extern "C" void kernel_launch(void* const* d_in, const int* in_sizes, int n_in,
                              void* d_out, int out_size, void* d_ws, size_t ws_size,
                              hipStream_t stream) {
  const float* x      = (const float*)d_in[0];
  const int*   idx    = (const int*)d_in[1];
  const float* norm_w = (const float*)d_in[2];
  const float* w1     = (const float*)d_in[3];
  const float* b1     = (const float*)d_in[4];
  const float* amp    = (const float*)d_in[5];
  const float* freq   = (const float*)d_in[6];
  const float* decay  = (const float*)d_in[7];
  const float* w2     = (const float*)d_in[8];
  const float* b2     = (const float*)d_in[9];
  const float* alpha  = (const float*)d_in[10];
  float* out = (float*)d_out;

  const size_t need = 2ull * FDIM * KNZ * sizeof(int2);  // 512 KB
  if (ws_size >= need) {
    int2* pr1 = (int2*)d_ws;
    int2* pr2 = pr1 + (size_t)FDIM * KNZ;
    geo_prep<<<FDIM / 16, 256, 0, stream>>>(idx, w1, w2, pr1, pr2);
    geo_main<true><<<NROWS / RB, TPB, 0, stream>>>(
        x, norm_w, b1, amp, freq, decay, b2, alpha, pr1, pr2, idx, w1, w2, out);
  } else {
    geo_main<false><<<NROWS / RB, TPB, 0, stream>>>(
        x, norm_w, b1, amp, freq, decay, b2, alpha, nullptr, nullptr, idx, w1, w2, out);
  }
}